// Round 15
// baseline (4624.736 us; speedup 1.0000x reference)
//
#include <hip/hip_runtime.h>
#include <stdint.h>

// Problem dims
#define Tn 512
#define Bn 128
#define NTOK (Bn*Tn)     // 65536
#define En 300
#define Hn 300
#define On 9
#define KP 320           // k-padded length: emb 300->320; h: 5 slices x 64
#define LDK 328          // LDS row stride in shorts (656 B rows, 16B-aligned)
#define HS 60            // hidden units per slice
#define SLP 64           // padded columns per slice in h-exchange layout
#define NSL 5            // slices per direction (5*60 = 300)
#define NCH 8            // batch chunks
#define MC 16            // batch rows per chunk (one m-tile)
#define NG 240           // 4*HS gate columns per block
#define NBLK (2*NCH*NSL) // 80 blocks
#define NTHR 960         // 15 waves = 1 m-tile x 15 n-tiles; == MC*HS cell threads

typedef short s4v __attribute__((ext_vector_type(4)));
typedef short s8v __attribute__((ext_vector_type(8)));
typedef float f4v __attribute__((ext_vector_type(4)));

// ---- static device scratch (d_ws unused) ----
__device__ unsigned short g_hcat[NTOK * 2 * Hn];   // 78,643,200 B — h outputs
__device__ unsigned short g_hx[2 * 2 * Bn * KP];   //    327,680 B — [dir][slot][Bn][KP] (padded slices)
__device__ int            g_flags[2 * NCH * NSL];  //        320 B — per-(dir,chunk) slice flags

__device__ inline float b2f(unsigned short u){ unsigned v = ((unsigned)u) << 16; float f; __builtin_memcpy(&f, &v, 4); return f; }
__device__ inline unsigned short f2b(float f){ unsigned u; __builtin_memcpy(&u, &f, 4); u = u + 0x7fffu + ((u >> 16) & 1u); return (unsigned short)(u >> 16); }
__device__ inline float sigf(float x){ return 1.f / (1.f + __expf(-x)); }
__device__ inline float tanh_f(float x){ return 2.f / (1.f + __expf(-2.f * x)) - 1.f; }

// ---------------- K0: zero h-exchange + flags ----------------
__global__ __launch_bounds__(256) void k_zero()
{
    const int i = blockIdx.x * 256 + threadIdx.x;
    const int stride = gridDim.x * 256;
    unsigned int* hp = (unsigned int*)g_hx;
    for (int j = i; j < (2 * 2 * Bn * KP) / 2; j += stride) hp[j] = 0u;   // pads stay 0 forever
    for (int j = i; j < 2 * NCH * NSL; j += stride) g_flags[j] = 0;
}

// ---------------- K1: fused bidirectional LSTM recurrence ----------------
// Per-(dir,chunk) groups of 5 blocks. h exchange uses 64-col padded slices so
// the consumer can stage each producer's tile AS ITS FLAG LANDS (skew overlap).
// Lane-0-only polling (15x less LLC flag pressure). Protocol else = r14.
__global__ __launch_bounds__(NTHR) void k_lstm(
    const int* __restrict__ x, const float* __restrict__ emb,
    const float* __restrict__ W_ih_f, const float* __restrict__ W_hh_f, const float* __restrict__ b_f,
    const float* __restrict__ W_ih_b, const float* __restrict__ W_hh_b, const float* __restrict__ b_b)
{
    const int bi    = blockIdx.x;
    const int dir   = bi / (NCH * NSL);
    const int rem   = bi % (NCH * NSL);
    const int chunk = rem / NSL;
    const int slice = rem % NSL;
    const int j0    = slice * HS;       // semantic hidden base (60-grid)
    const int b0    = chunk * MC;

    const float* Wih  = dir ? W_ih_b : W_ih_f;
    const float* Whh  = dir ? W_hh_b : W_hh_f;
    const float* bias = dir ? b_b    : b_f;
    unsigned short* hxd = g_hx + dir * (2 * Bn * KP);
    int* myf = g_flags + (dir * NCH + chunk) * NSL;

    __shared__ __align__(16) unsigned short Aemb[2][MC * LDK]; // 21 KB emb staging, double-buffered
    __shared__ __align__(16) unsigned short Hb[MC * LDK];      // 10.5 KB h staging (padded-slice layout)
    __shared__ __align__(16) float Gsm[MC * NG];               // 15.4 KB gate dump

    const int tid  = threadIdx.x;
    const int lane = tid & 63;
    const int wid  = tid >> 6;              // 15 waves
    const int n0   = wid * 16;              // 15 n-tiles (240 gate cols); single m-tile
    const int kq   = (lane >> 4) * 8;       // k-subgroup within 32

    // ---- preload weight B-fragments (fp32 -> bf16 once, weight-stationary) ----
    // local gate col layout: [i(60) | f(60) | g(60) | o(60)]
    const int nloc = n0 + (lane & 15);      // 0..239
    const int q    = nloc / HS;             // gate index 0..3
    const int jjn  = nloc % HS;
    const int grow = q * Hn + j0 + jjn;     // global row in [1200]
    s8v bih[10], bhh[10];
#pragma unroll
    for (int kc = 0; kc < 10; kc++) {
        int kb = kc * 32 + kq;
        s8v fi = {0,0,0,0,0,0,0,0}, fh = {0,0,0,0,0,0,0,0};
#pragma unroll
        for (int j = 0; j < 8; j++) {
            int k = kb + j;
            // bih: dense emb k-layout (0..299 valid)
            if (k < En) fi[j] = (short)f2b(Wih[grow * En + k]);
            // bhh: padded-slice h layout: k = 64*sl + i, semantic col = 60*sl + i (i<60)
            int sl = k >> 6, ii = k & 63;
            if (ii < HS) fh[j] = (short)f2b(Whh[grow * Hn + HS * sl + ii]);
        }
        bih[kc] = fi; bhh[kc] = fh;
    }

    // ---- per-thread cell state: tid <-> (batch row ebl, unit ejj); NTHR == MC*HS ----
    const int ebl = tid / HS;   // 0..15
    const int ejj = tid % HS;   // 0..59
    const float bi_i = bias[0 * Hn + j0 + ejj];
    const float bi_f = bias[1 * Hn + j0 + ejj];
    const float bi_g = bias[2 * Hn + j0 + ejj];
    const float bi_o = bias[3 * Hn + j0 + ejj];
    float creg = 0.f;
    const bool pub = ((ejj & 1) == 0);      // even-ejj lanes store packed dwords
    // pairs (even ejj, ejj+1): last lane of every wave has odd ejj -> no wave-crossing

    // ---- prologue: stage emb for s=0 into Aemb[0] ----
    {
        const int t0 = dir ? (Tn - 1) : 0;
        for (int i = tid; i < MC * 80; i += NTHR) {
            int r = i / 80, c = i - r * 80;
            s4v v = {0, 0, 0, 0};
            if (c < 75) {
                int xi = x[(b0 + r) * Tn + t0];
                float4 f = *(const float4*)(emb + (size_t)xi * En + c * 4);
                v[0] = (short)f2b(f.x); v[1] = (short)f2b(f.y);
                v[2] = (short)f2b(f.z); v[3] = (short)f2b(f.w);
            }
            *(s4v*)&Aemb[0][r * LDK + c * 4] = v;
        }
        __syncthreads();
    }

    // staging assignment for one 16x64-short slice tile: 512 dwords, tids 0..511
    const int str = tid >> 5;          // row 0..15 (for tid < 512)
    const int stc = tid & 31;          // dword col 0..31

#pragma unroll 1
    for (int s = 0; s < Tn; s++) {
        const int t   = dir ? (Tn - 1 - s) : s;
        const int cur = s & 1, nxt = cur ^ 1;

        // issue emb prefetch for step s+1 into registers FIRST (max overlap)
        float4 pf[2];
        const bool do_pf = (s + 1 < Tn);
        if (do_pf) {
            const int tn1 = dir ? (Tn - 2 - s) : (s + 1);
#pragma unroll
            for (int k = 0; k < 2; k++) {
                int i = tid + k * NTHR;
                if (i < MC * 80) {
                    int r = i / 80, c = i - r * 80;
                    if (c < 75) {
                        int xi = x[(b0 + r) * Tn + tn1];
                        pf[k] = *(const float4*)(emb + (size_t)xi * En + c * 4);
                    }
                }
            }
        }

        // MFMA1: input projection part from Aemb[cur]
        f4v acc = {0.f, 0.f, 0.f, 0.f};
        {
            const unsigned short* abase = &Aemb[cur][(lane & 15) * LDK + kq];
#pragma unroll
            for (int kc = 0; kc < 10; kc++) {
                s8v a = *(const s8v*)(abase + kc * 32);
                acc = __builtin_amdgcn_mfma_f32_16x16x32_bf16(a, bih[kc], acc, 0, 0, 0);
            }
        }

        // P3 pipelined: per slice, lane-0 spin then stage that slice's tile
        {
            const unsigned int* hsrc = (const unsigned int*)(hxd + (s & 1) * (Bn * KP));
#pragma unroll 1
            for (int sl = 0; sl < NSL; sl++) {
                if (lane == 0) {
                    while (__hip_atomic_load(&myf[sl], __ATOMIC_RELAXED, __HIP_MEMORY_SCOPE_AGENT) < s) { }
                }
                // wave reconverges here; stage slice sl (tids 0..511 carry the tile)
                if (tid < 512) {
                    unsigned int v = __hip_atomic_load(hsrc + (b0 + str) * (KP / 2) + 32 * sl + stc,
                                                       __ATOMIC_RELAXED, __HIP_MEMORY_SCOPE_AGENT);
                    *(unsigned int*)&Hb[str * LDK + SLP * sl + 2 * stc] = v;
                }
            }
        }
        __syncthreads();   // bar B: Hb fully staged

        // MFMA2: recurrent part from Hb (padded-slice k-layout matches bhh)
        {
            const unsigned short* abase = &Hb[(lane & 15) * LDK + kq];
#pragma unroll
            for (int kc = 0; kc < 10; kc++) {
                s8v a = *(const s8v*)(abase + kc * 32);
                acc = __builtin_amdgcn_mfma_f32_16x16x32_bf16(a, bhh[kc], acc, 0, 0, 0);
            }
        }

        // dump gates (C layout: col=lane&15, row=(lane>>4)*4+reg; single m-tile)
        {
            int col   = n0 + (lane & 15);
            int rbase = (lane >> 4) * 4;
#pragma unroll
            for (int r2 = 0; r2 < 4; r2++) Gsm[(rbase + r2) * NG + col] = acc[r2];
        }
        __syncthreads();   // bar C: Gsm ready

        // elementwise LSTM cell + hx publish (shfl-paired dword stores, padded cols)
        unsigned int pkt = 0u;
        {
            float gi  = Gsm[ebl * NG + 0 * HS + ejj] + bi_i;
            float gf  = Gsm[ebl * NG + 1 * HS + ejj] + bi_f;
            float gg2 = Gsm[ebl * NG + 2 * HS + ejj] + bi_g;
            float go  = Gsm[ebl * NG + 3 * HS + ejj] + bi_o;
            float iv = sigf(gi), fv = sigf(gf), gv = tanh_f(gg2), ov = sigf(go);
            creg = fv * creg + iv * gv;
            float h = ov * tanh_f(creg);
            float hn = __shfl_down(h, 1);          // partner (ejj+1) in same wave
            if (pub) {
                pkt = (unsigned int)f2b(h) | ((unsigned int)f2b(hn) << 16);
                // h exchange (other parity slot), padded col = 64*slice + ejj
                __hip_atomic_store((unsigned int*)(hxd + ((s + 1) & 1) * (Bn * KP))
                                       + (b0 + ebl) * (KP / 2) + 32 * slice + ejj / 2,
                                   pkt, __ATOMIC_RELAXED, __HIP_MEMORY_SCOPE_AGENT);
            }
        }

        // writeback prefetched emb(s+1) -> Aemb[nxt] (covered by bar D)
        if (do_pf) {
#pragma unroll
            for (int k = 0; k < 2; k++) {
                int i = tid + k * NTHR;
                if (i < MC * 80) {
                    int r = i / 80, c = i - r * 80;
                    s4v v = {0, 0, 0, 0};
                    if (c < 75) {
                        v[0] = (short)f2b(pf[k].x); v[1] = (short)f2b(pf[k].y);
                        v[2] = (short)f2b(pf[k].z); v[3] = (short)f2b(pf[k].w);
                    }
                    *(s4v*)&Aemb[nxt][r * LDK + c * 4] = v;
                }
            }
        }
        __syncthreads();   // bar D: drains vmcnt (hx stores at LLC); Aemb[nxt] visible

        // flag first (shortest publish->detect path), hcat after (fire-and-forget)
        if (tid == 0) {
            __hip_atomic_store(&myf[slice], s + 1, __ATOMIC_RELAXED, __HIP_MEMORY_SCOPE_AGENT);
        }
        if (pub) {
            __hip_atomic_store((unsigned int*)g_hcat
                                   + (((size_t)((b0 + ebl) * Tn + t)) * (2 * Hn) + dir * Hn + j0 + ejj) / 2,
                               pkt, __ATOMIC_RELAXED, __HIP_MEMORY_SCOPE_AGENT);
        }
    }
}

// ---------------- K2: fused out-projection + softmax, one wave per 16 positions ----------------
__global__ __launch_bounds__(256) void k_out(
    const float* __restrict__ W_lin, const float* __restrict__ b_lin, float* __restrict__ out)
{
    __shared__ float Wl[On * 2 * Hn];  // 21.6 KB
    __shared__ float bl[On];
    const int tid = threadIdx.x;
    for (int i = tid; i < On * 2 * Hn; i += 256) Wl[i] = W_lin[i];
    if (tid < On) bl[tid] = b_lin[tid];
    __syncthreads();

    const int lane = tid & 63;
    const int w    = tid >> 6;
    const int wg   = blockIdx.x * 4 + w;      // 4096 waves
    for (int it = 0; it < 16; it++) {
        const int p = wg * 16 + it;           // 0..65535
        const unsigned short* row = g_hcat + (size_t)p * (2 * Hn);
        float part[On];
#pragma unroll
        for (int o = 0; o < On; o++) part[o] = 0.f;
        for (int c = 0; c < 10; c++) {
            int k = lane + 64 * c;
            if (k < 2 * Hn) {
                float v = b2f(row[k]);
#pragma unroll
                for (int o = 0; o < On; o++) part[o] += v * Wl[o * (2 * Hn) + k];
            }
        }
#pragma unroll
        for (int off = 32; off >= 1; off >>= 1) {
#pragma unroll
            for (int o = 0; o < On; o++) part[o] += __shfl_xor(part[o], off, 64);
        }
        if (lane == 0) {
            float lg[On];
            float m = -1e30f;
#pragma unroll
            for (int o = 0; o < On; o++) { lg[o] = part[o] + bl[o]; m = fmaxf(m, lg[o]); }
            float ssum = 0.f;
#pragma unroll
            for (int o = 0; o < On; o++) { lg[o] = __expf(lg[o] - m); ssum += lg[o]; }
            float inv = 1.f / ssum;
#pragma unroll
            for (int o = 0; o < On; o++) out[(size_t)p * On + o] = lg[o] * inv;
        }
    }
}

// ---------------- host launcher ----------------
extern "C" void kernel_launch(void* const* d_in, const int* in_sizes, int n_in,
                              void* d_out, int out_size, void* d_ws, size_t ws_size,
                              hipStream_t stream)
{
    (void)in_sizes; (void)n_in; (void)out_size; (void)d_ws; (void)ws_size;
    const int* x = (const int*)d_in[0];
    const float* emb   = (const float*)d_in[1];
    const float* Wih_f = (const float*)d_in[2];
    const float* Whh_f = (const float*)d_in[3];
    const float* bf    = (const float*)d_in[4];
    const float* Wih_b = (const float*)d_in[5];
    const float* Whh_b = (const float*)d_in[6];
    const float* bb    = (const float*)d_in[7];
    const float* Wlin  = (const float*)d_in[8];
    const float* blin  = (const float*)d_in[9];
    float* out = (float*)d_out;

    k_zero<<<128, 256, 0, stream>>>();

    void* args[] = {
        (void*)&x, (void*)&emb,
        (void*)&Wih_f, (void*)&Whh_f, (void*)&bf,
        (void*)&Wih_b, (void*)&Whh_b, (void*)&bb
    };
    hipLaunchCooperativeKernel((const void*)k_lstm, dim3(NBLK), dim3(NTHR), args, 0, stream);

    k_out<<<1024, 256, 0, stream>>>(Wlin, blin, out);
}

// Round 16
// 2660.116 us; speedup vs baseline: 1.7385x; 1.7385x over previous
//
#include <hip/hip_runtime.h>
#include <stdint.h>

// Problem dims
#define Tn 512
#define Bn 128
#define NTOK (Bn*Tn)     // 65536
#define En 300
#define Hn 300
#define On 9
#define KP 320           // K padded to 10*32
#define LDK 328          // LDS row stride in shorts (656 B rows, 16B-aligned)
#define HS 60            // hidden units per slice
#define NSL 5            // slices per direction (5*60 = 300)
#define NCH 8            // batch chunks
#define MC 16            // batch rows per chunk (one m-tile)
#define NG 240           // 4*HS gate columns per block
#define NBLK (2*NCH*NSL) // 80 blocks
#define NTHR 960         // 15 waves = 1 m-tile x 15 n-tiles; == MC*HS cell threads

typedef short s4v __attribute__((ext_vector_type(4)));
typedef short s8v __attribute__((ext_vector_type(8)));
typedef float f4v __attribute__((ext_vector_type(4)));

// ---- static device scratch (d_ws unused) ----
__device__ unsigned short g_hcat[NTOK * 2 * Hn];   // 78,643,200 B — h outputs
__device__ unsigned short g_hx[2 * 2 * Bn * KP];   //    327,680 B — [dir][slot][Bn][KP]
__device__ int            g_flags[2 * NCH * NSL];  //        320 B — per-(dir,chunk) slice flags

__device__ inline float b2f(unsigned short u){ unsigned v = ((unsigned)u) << 16; float f; __builtin_memcpy(&f, &v, 4); return f; }
__device__ inline unsigned short f2b(float f){ unsigned u; __builtin_memcpy(&u, &f, 4); u = u + 0x7fffu + ((u >> 16) & 1u); return (unsigned short)(u >> 16); }
__device__ inline float sigf(float x){ return 1.f / (1.f + __expf(-x)); }
__device__ inline float tanh_f(float x){ return 2.f / (1.f + __expf(-2.f * x)) - 1.f; }

// ---------------- K0: zero h-exchange + flags ----------------
__global__ __launch_bounds__(256) void k_zero()
{
    const int i = blockIdx.x * 256 + threadIdx.x;
    const int stride = gridDim.x * 256;
    unsigned int* hp = (unsigned int*)g_hx;
    for (int j = i; j < (2 * 2 * Bn * KP) / 2; j += stride) hp[j] = 0u;
    for (int j = i; j < 2 * NCH * NSL; j += stride) g_flags[j] = 0;
}

// ---------------- K1: fused bidirectional LSTM recurrence ----------------
// R14 dataflow (bulk parallel P3, all-lane poll). __launch_bounds__(_, 4)
// lifts the VGPR cap 64->128: with 80 blocks on 256 CUs every block has its
// own CU, so 8-wave/SIMD occupancy is worthless — spend registers on hoisting
// the emb prefetch off the critical path instead.
__global__ __launch_bounds__(NTHR, 4) void k_lstm(
    const int* __restrict__ x, const float* __restrict__ emb,
    const float* __restrict__ W_ih_f, const float* __restrict__ W_hh_f, const float* __restrict__ b_f,
    const float* __restrict__ W_ih_b, const float* __restrict__ W_hh_b, const float* __restrict__ b_b)
{
    const int bi    = blockIdx.x;
    const int dir   = bi / (NCH * NSL);
    const int rem   = bi % (NCH * NSL);
    const int chunk = rem / NSL;
    const int slice = rem % NSL;
    const int j0    = slice * HS;
    const int b0    = chunk * MC;

    const float* Wih  = dir ? W_ih_b : W_ih_f;
    const float* Whh  = dir ? W_hh_b : W_hh_f;
    const float* bias = dir ? b_b    : b_f;
    unsigned short* hxd = g_hx + dir * (2 * Bn * KP);
    int* myf = g_flags + (dir * NCH + chunk) * NSL;

    __shared__ __align__(16) unsigned short Aemb[2][MC * LDK]; // 21 KB emb staging, double-buffered
    __shared__ __align__(16) unsigned short Hb[MC * LDK];      // 10.5 KB h staging
    __shared__ __align__(16) float Gsm[MC * NG];               // 15.4 KB gate dump

    const int tid  = threadIdx.x;
    const int lane = tid & 63;
    const int wid  = tid >> 6;              // 15 waves
    const int n0   = wid * 16;              // 15 n-tiles (240 gate cols); single m-tile
    const int kq   = (lane >> 4) * 8;       // k-subgroup within 32

    // ---- preload weight B-fragments (fp32 -> bf16 once, weight-stationary) ----
    // local gate col layout: [i(60) | f(60) | g(60) | o(60)]
    const int nloc = n0 + (lane & 15);      // 0..239
    const int q    = nloc / HS;             // gate index 0..3
    const int jjn  = nloc % HS;
    const int grow = q * Hn + j0 + jjn;     // global row in [1200]
    s8v bih[10], bhh[10];
#pragma unroll
    for (int kc = 0; kc < 10; kc++) {
        int kb = kc * 32 + kq;
        s8v fi = {0,0,0,0,0,0,0,0}, fh = {0,0,0,0,0,0,0,0};
#pragma unroll
        for (int j = 0; j < 8; j++) {
            int k = kb + j;
            if (k < En) {
                fi[j] = (short)f2b(Wih[grow * En + k]);
                fh[j] = (short)f2b(Whh[grow * Hn + k]);
            }
        }
        bih[kc] = fi; bhh[kc] = fh;
    }

    // ---- per-thread cell state: tid <-> (batch row ebl, unit ejj); NTHR == MC*HS ----
    const int ebl = tid / HS;   // 0..15
    const int ejj = tid % HS;   // 0..59
    const float bi_i = bias[0 * Hn + j0 + ejj];
    const float bi_f = bias[1 * Hn + j0 + ejj];
    const float bi_g = bias[2 * Hn + j0 + ejj];
    const float bi_o = bias[3 * Hn + j0 + ejj];
    float creg = 0.f;
    const bool pub = ((ejj & 1) == 0);      // even-ejj lanes store packed dwords
    // pairs are (even ejj, ejj+1); the last lane of every wave has odd ejj -> no
    // pair crosses a wave boundary.

    // ---- prologue: stage emb for s=0 into Aemb[0] ----
    {
        const int t0 = dir ? (Tn - 1) : 0;
        for (int i = tid; i < MC * 80; i += NTHR) {
            int r = i / 80, c = i - r * 80;
            s4v v = {0, 0, 0, 0};
            if (c < 75) {
                int xi = x[(b0 + r) * Tn + t0];
                float4 f = *(const float4*)(emb + (size_t)xi * En + c * 4);
                v[0] = (short)f2b(f.x); v[1] = (short)f2b(f.y);
                v[2] = (short)f2b(f.z); v[3] = (short)f2b(f.w);
            }
            *(s4v*)&Aemb[0][r * LDK + c * 4] = v;
        }
        __syncthreads();
    }

#pragma unroll 1
    for (int s = 0; s < Tn; s++) {
        const int t   = dir ? (Tn - 1 - s) : s;
        const int cur = s & 1, nxt = cur ^ 1;

        // issue emb prefetch for step s+1 into registers FIRST (max overlap)
        float4 pf[2];
        const bool do_pf = (s + 1 < Tn);
        if (do_pf) {
            const int tn1 = dir ? (Tn - 2 - s) : (s + 1);
#pragma unroll
            for (int k = 0; k < 2; k++) {
                int i = tid + k * NTHR;            // < 1920; valid when < 1280 = MC*80
                if (i < MC * 80) {
                    int r = i / 80, c = i - r * 80;
                    if (c < 75) {
                        int xi = x[(b0 + r) * Tn + tn1];
                        pf[k] = *(const float4*)(emb + (size_t)xi * En + c * 4);
                    }
                }
            }
        }

        // MFMA1: input projection part from Aemb[cur]
        f4v acc = {0.f, 0.f, 0.f, 0.f};
        {
            const unsigned short* abase = &Aemb[cur][(lane & 15) * LDK + kq];
#pragma unroll
            for (int kc = 0; kc < 10; kc++) {
                s8v a = *(const s8v*)(abase + kc * 32);
                acc = __builtin_amdgcn_mfma_f32_16x16x32_bf16(a, bih[kc], acc, 0, 0, 0);
            }
        }

        // per-wave pure-spin poll: all 5 slices of this (dir,chunk) group published h_s
        if (lane < NSL) {
            while (__hip_atomic_load(&myf[lane], __ATOMIC_RELAXED, __HIP_MEMORY_SCOPE_AGENT) < s) { }
        }

        // P3: stage h_s from parity slot into Hb (LLC-coherent dword loads, bulk parallel)
        {
            const unsigned short* hsrc = hxd + (s & 1) * (Bn * KP) + b0 * KP;
            for (int i = tid; i < MC * 160; i += NTHR) {
                int r = i / 160, c = i - r * 160;
                unsigned int v = __hip_atomic_load((const unsigned int*)(hsrc + r * KP) + c,
                                                   __ATOMIC_RELAXED, __HIP_MEMORY_SCOPE_AGENT);
                *(unsigned int*)&Hb[r * LDK + c * 2] = v;
            }
        }
        __syncthreads();   // bar B: Hb ready

        // MFMA2: recurrent part from Hb
        {
            const unsigned short* abase = &Hb[(lane & 15) * LDK + kq];
#pragma unroll
            for (int kc = 0; kc < 10; kc++) {
                s8v a = *(const s8v*)(abase + kc * 32);
                acc = __builtin_amdgcn_mfma_f32_16x16x32_bf16(a, bhh[kc], acc, 0, 0, 0);
            }
        }

        // dump gates (C layout: col=lane&15, row=(lane>>4)*4+reg; single m-tile)
        {
            int col   = n0 + (lane & 15);
            int rbase = (lane >> 4) * 4;
#pragma unroll
            for (int r2 = 0; r2 < 4; r2++) Gsm[(rbase + r2) * NG + col] = acc[r2];
        }
        __syncthreads();   // bar C: Gsm ready

        // elementwise LSTM cell + hx publish (shfl-paired dword stores)
        unsigned int pkt = 0u;
        {
            float gi  = Gsm[ebl * NG + 0 * HS + ejj] + bi_i;
            float gf  = Gsm[ebl * NG + 1 * HS + ejj] + bi_f;
            float gg2 = Gsm[ebl * NG + 2 * HS + ejj] + bi_g;
            float go  = Gsm[ebl * NG + 3 * HS + ejj] + bi_o;
            float iv = sigf(gi), fv = sigf(gf), gv = tanh_f(gg2), ov = sigf(go);
            creg = fv * creg + iv * gv;
            float h = ov * tanh_f(creg);
            float hn = __shfl_down(h, 1);          // partner (ejj+1) in same wave
            if (pub) {
                pkt = (unsigned int)f2b(h) | ((unsigned int)f2b(hn) << 16);
                // h exchange (other parity slot) — the only store that must drain at bar D
                __hip_atomic_store((unsigned int*)(hxd + ((s + 1) & 1) * (Bn * KP))
                                       + (b0 + ebl) * (KP / 2) + (j0 + ejj) / 2,
                                   pkt, __ATOMIC_RELAXED, __HIP_MEMORY_SCOPE_AGENT);
            }
        }

        // writeback prefetched emb(s+1) -> Aemb[nxt] (covered by bar D)
        if (do_pf) {
#pragma unroll
            for (int k = 0; k < 2; k++) {
                int i = tid + k * NTHR;
                if (i < MC * 80) {
                    int r = i / 80, c = i - r * 80;
                    s4v v = {0, 0, 0, 0};
                    if (c < 75) {
                        v[0] = (short)f2b(pf[k].x); v[1] = (short)f2b(pf[k].y);
                        v[2] = (short)f2b(pf[k].z); v[3] = (short)f2b(pf[k].w);
                    }
                    *(s4v*)&Aemb[nxt][r * LDK + c * 4] = v;
                }
            }
        }
        __syncthreads();   // bar D: drains vmcnt (hx stores at LLC); Aemb[nxt] visible

        // flag first (shortest publish->detect path), hcat after (fire-and-forget)
        if (tid == 0) {
            __hip_atomic_store(&myf[slice], s + 1, __ATOMIC_RELAXED, __HIP_MEMORY_SCOPE_AGENT);
        }
        if (pub) {
            __hip_atomic_store((unsigned int*)g_hcat
                                   + (((size_t)((b0 + ebl) * Tn + t)) * (2 * Hn) + dir * Hn + j0 + ejj) / 2,
                               pkt, __ATOMIC_RELAXED, __HIP_MEMORY_SCOPE_AGENT);
        }
    }
}

// ---------------- K2: fused out-projection + softmax, one wave per 16 positions ----------------
__global__ __launch_bounds__(256) void k_out(
    const float* __restrict__ W_lin, const float* __restrict__ b_lin, float* __restrict__ out)
{
    __shared__ float Wl[On * 2 * Hn];  // 21.6 KB
    __shared__ float bl[On];
    const int tid = threadIdx.x;
    for (int i = tid; i < On * 2 * Hn; i += 256) Wl[i] = W_lin[i];
    if (tid < On) bl[tid] = b_lin[tid];
    __syncthreads();

    const int lane = tid & 63;
    const int w    = tid >> 6;
    const int wg   = blockIdx.x * 4 + w;      // 4096 waves
    for (int it = 0; it < 16; it++) {
        const int p = wg * 16 + it;           // 0..65535
        const unsigned short* row = g_hcat + (size_t)p * (2 * Hn);
        float part[On];
#pragma unroll
        for (int o = 0; o < On; o++) part[o] = 0.f;
        for (int c = 0; c < 10; c++) {
            int k = lane + 64 * c;
            if (k < 2 * Hn) {
                float v = b2f(row[k]);
#pragma unroll
                for (int o = 0; o < On; o++) part[o] += v * Wl[o * (2 * Hn) + k];
            }
        }
#pragma unroll
        for (int off = 32; off >= 1; off >>= 1) {
#pragma unroll
            for (int o = 0; o < On; o++) part[o] += __shfl_xor(part[o], off, 64);
        }
        if (lane == 0) {
            float lg[On];
            float m = -1e30f;
#pragma unroll
            for (int o = 0; o < On; o++) { lg[o] = part[o] + bl[o]; m = fmaxf(m, lg[o]); }
            float ssum = 0.f;
#pragma unroll
            for (int o = 0; o < On; o++) { lg[o] = __expf(lg[o] - m); ssum += lg[o]; }
            float inv = 1.f / ssum;
#pragma unroll
            for (int o = 0; o < On; o++) out[(size_t)p * On + o] = lg[o] * inv;
        }
    }
}

// ---------------- host launcher ----------------
extern "C" void kernel_launch(void* const* d_in, const int* in_sizes, int n_in,
                              void* d_out, int out_size, void* d_ws, size_t ws_size,
                              hipStream_t stream)
{
    (void)in_sizes; (void)n_in; (void)out_size; (void)d_ws; (void)ws_size;
    const int* x = (const int*)d_in[0];
    const float* emb   = (const float*)d_in[1];
    const float* Wih_f = (const float*)d_in[2];
    const float* Whh_f = (const float*)d_in[3];
    const float* bf    = (const float*)d_in[4];
    const float* Wih_b = (const float*)d_in[5];
    const float* Whh_b = (const float*)d_in[6];
    const float* bb    = (const float*)d_in[7];
    const float* Wlin  = (const float*)d_in[8];
    const float* blin  = (const float*)d_in[9];
    float* out = (float*)d_out;

    k_zero<<<128, 256, 0, stream>>>();

    void* args[] = {
        (void*)&x, (void*)&emb,
        (void*)&Wih_f, (void*)&Whh_f, (void*)&bf,
        (void*)&Wih_b, (void*)&Whh_b, (void*)&bb
    };
    hipLaunchCooperativeKernel((const void*)k_lstm, dim3(NBLK), dim3(NTHR), args, 0, stream);

    k_out<<<1024, 256, 0, stream>>>(Wlin, blin, out);
}